// Round 11
// baseline (206.844 us; speedup 1.0000x reference)
//
#include <hip/hip_runtime.h>
#include <hip/hip_bf16.h>

// Problem geometry
#define N_ROWS 32000   // Q_OUT*Q_IN*NUM_P
#define SB     12      // SCALAR_BASIS
#define FC     720     // FILTER_C
#define FD     2704    // FILTER_DIM
#define OCOLS  2704    // DIM_OUT*DIM_IN
#define OPAD   2816    // OCOLS padded to 22*128
#define ANGD   25
#define PDIM   300     // SB * ANGD
#define KST    320     // PDIM padded to 5*64
#define NT     5       // K tiles of 64

typedef __attribute__((ext_vector_type(8))) short bf16x8;
typedef __attribute__((ext_vector_type(4))) float f32x4;

__device__ __forceinline__ void gload16(const void* g, void* l) {
    __builtin_amdgcn_global_load_lds(
        (const __attribute__((address_space(1))) void*)g,
        (__attribute__((address_space(3))) void*)l, 16, 0, 0);
}

// ---------------------------------------------------------------------------
// Merged prep kernel: blocks [0, OPAD) run build_V, blocks [OPAD, OPAD+4000)
// run build_X (was two serialized launches ~20 us; now overlapped).
// ---------------------------------------------------------------------------
__global__ __launch_bounds__(320) void prep(
    const float* __restrict__ TP,
    const float* __restrict__ W,
    const float* __restrict__ sk,
    const float* __restrict__ ang,
    __hip_bfloat16* __restrict__ V,
    __hip_bfloat16* __restrict__ X)
{
    const int tid = threadIdx.x;  // 0..319
    if (blockIdx.x < OPAD) {
        // ---- build_V: V[o, s*25+a] = sum_c TP[o,...] * (W[s,...]/sqrt(12))
        const int o = blockIdx.x;
        __shared__ float s_tp[FD];        // 10816 B
        __shared__ float s_w[SB * FC];    // 34560 B

        const float inv = 0.28867513459481288f; // 1/sqrt(12)
        for (int i = tid; i < SB * FC; i += 320) s_w[i] = W[i] * inv;
        if (o < OCOLS) {
            for (int i = tid; i < FD; i += 320) s_tp[i] = TP[(size_t)o * FD + i];
        } else {
            for (int i = tid; i < FD; i += 320) s_tp[i] = 0.f;
        }
        __syncthreads();

        const int p = tid;   // one p per thread
        float acc = 0.f;
        if (p < PDIM) {
            const int s     = p / ANGD;
            const int alpha = p - s * ANGD;
            int m, off, sco, al, Cl;
            if (alpha < 1)       { m = 1; off = 0;    sco = 0;   al = 0;  Cl = 144; }
            else if (alpha < 4)  { m = 3; off = 144;  sco = 144; al = 1;  Cl = 272; }
            else if (alpha < 9)  { m = 5; off = 960;  sco = 416; al = 4;  Cl = 208; }
            else if (alpha < 16) { m = 7; off = 2000; sco = 624; al = 9;  Cl = 80;  }
            else                 { m = 9; off = 2560; sco = 704; al = 16; Cl = 16;  }
            const int j = alpha - al;
            const float* tp = s_tp + off + j;
            const float* ww = s_w + s * FC + sco;
            float a0 = 0.f, a1 = 0.f, a2 = 0.f, a3 = 0.f;
            for (int c = 0; c < Cl; c += 4) {
                a0 += tp[(c + 0) * m] * ww[c + 0];
                a1 += tp[(c + 1) * m] * ww[c + 1];
                a2 += tp[(c + 2) * m] * ww[c + 2];
                a3 += tp[(c + 3) * m] * ww[c + 3];
            }
            acc = (a0 + a1) + (a2 + a3);
        }
        if (p < KST) V[(size_t)o * KST + p] = __float2bfloat16(acc);
    } else {
        // ---- build_X: X[n, s*25+a] = sk[n,s] * ang[n,a]
        const int idx = (blockIdx.x - OPAD) * 320 + tid;   // 4000 blocks x 320 = 1.28M
        if (idx >= N_ROWS * (KST / 8)) return;
        const int n  = idx / (KST / 8);
        const int p0 = (idx - n * (KST / 8)) * 8;
        const float* skn  = sk  + (size_t)n * SB;
        const float* angn = ang + (size_t)n * ANGD;
        alignas(16) __hip_bfloat16 tmp[8];
        #pragma unroll
        for (int u = 0; u < 8; ++u) {
            const int p = p0 + u;
            float v = 0.f;
            if (p < PDIM) {
                const int s = p / ANGD;
                const int a = p - s * ANGD;
                v = skn[s] * angn[a];
            }
            tmp[u] = __float2bfloat16(v);
        }
        *(bf16x8*)(X + (size_t)n * KST + p0) = *(const bf16x8*)tmp;
    }
}

// ---------------------------------------------------------------------------
// GEMM: 128x128 tile, K=320, 8 waves (2M x 4N). A staged via swizzled
// global_load_lds (unchanged). B (V, 1.76 MB L2-resident) read DIRECTLY
// global->VGPR, prefetched one K-tile ahead (reg double-buffer, full
// unroll -> static indexing). Removes 240 KB/block of LDS traffic (B
// stage-writes + bfr ds_reads). nt stores via LDS-routed full-line
// epilogue (round-9 proven best).
// vmcnt ledger (per wave): pro {A0(2),A1(2),B0(4)} vmcnt(0);
// iter t: +B(t+1)(4) ... +A(t+2)(2); end: vmcnt(2) leaves A(t+2) only
// (t=NT-2: vmcnt(0)).
// ---------------------------------------------------------------------------
__global__ __launch_bounds__(512, 4) void gemm_bt(
    const __hip_bfloat16* __restrict__ A,   // X: (N_ROWS, KST)
    const __hip_bfloat16* __restrict__ B,   // V: (OPAD, KST)
    float* __restrict__ C)
{
    __shared__ __align__(1024) char lds[34816];
    char* const bufA = lds;            // 2 x 16384 B (A dbuf)
    float* const s_c = (float*)lds;    // epilogue alias: [64][132] f32 (33792 B)

    const int tid  = threadIdx.x;
    const int wave = tid >> 6;
    const int lane = tid & 63;

    const int bn = blockIdx.x;         // 22 col tiles
    const int bm = blockIdx.y;         // 250 row tiles
    const size_t arow0 = (size_t)bm * 128;
    const size_t brow0 = (size_t)bn * 128;

    const int wr = wave >> 2;   // 0..1 (M half: 64 rows)
    const int wc = wave & 3;    // 0..3 (N quarter: 32 cols)

    // A staging (LDS linear dest; global source pre-swizzled)
    const int lrow  = lane >> 3;
    const int lslot = ((lane & 7) ^ (lrow & 7)) << 4;
    auto STAGE_A = [&](int t, char* lbase) {
        const char* g0 = (const char*)A
            + (arow0 + (size_t)(wave * 8 + lrow)) * (KST * 2)
            + (size_t)t * 128 + lslot;
        gload16(g0,                          lbase + wave * 1024);
        gload16(g0 + (size_t)64 * (KST * 2), lbase + 8192 + wave * 1024);
    };

    // reader lane constants (swizzle: slot = (ks*4+koct) ^ (row&7))
    const int rl   = lane & 15;
    const int koct = lane >> 4;
    const int sK0 = ((0 * 4 + koct) ^ (lane & 7)) << 4;
    const int sK1 = ((1 * 4 + koct) ^ (lane & 7)) << 4;

    // B direct-global lane bases (bytes): row = brow0 + wc*32 + n*16 + rl
    const char* const Bb = (const char*)B;
    const size_t boff0 = (brow0 + (size_t)(wc * 32 + 0 * 16 + rl)) * (KST * 2) + koct * 16;
    const size_t boff1 = (brow0 + (size_t)(wc * 32 + 1 * 16 + rl)) * (KST * 2) + koct * 16;

    bf16x8 bfr[2][2][2];   // [t&1][n][ks] — full unroll keeps indices static
    auto LOADB = [&](int t, int slot) {
        bfr[slot][0][0] = *(const bf16x8*)(Bb + boff0 + t * 128 + 0);
        bfr[slot][0][1] = *(const bf16x8*)(Bb + boff0 + t * 128 + 64);
        bfr[slot][1][0] = *(const bf16x8*)(Bb + boff1 + t * 128 + 0);
        bfr[slot][1][1] = *(const bf16x8*)(Bb + boff1 + t * 128 + 64);
    };

    // prologue: A0 -> buf0, A1 -> buf1, B0 -> regs
    STAGE_A(0, bufA + 0);
    STAGE_A(1, bufA + 16384);
    LOADB(0, 0);
    asm volatile("s_waitcnt vmcnt(0)" ::: "memory");
    __builtin_amdgcn_s_barrier();

    f32x4 acc[4][2] = {};   // [m][n]; D^T frags: row=o, col=M

    #pragma unroll
    for (int t = 0; t < NT; ++t) {
        char* const aC = bufA + (t & 1) * 16384;

        if (t + 1 < NT) LOADB(t + 1, (t + 1) & 1);   // prefetch next B

        bf16x8 af[4][2];
        #pragma unroll
        for (int m = 0; m < 4; ++m) {
            const int r = wr * 64 + m * 16 + rl;
            af[m][0] = *(const bf16x8*)(aC + r * 128 + sK0);
            af[m][1] = *(const bf16x8*)(aC + r * 128 + sK1);
        }
        asm volatile("s_waitcnt lgkmcnt(0)" ::: "memory");
        __builtin_amdgcn_sched_barrier(0);
        __builtin_amdgcn_s_barrier();   // all waves done reading this buf

        if (t + 2 < NT) STAGE_A(t + 2, aC);   // refill the buffer just read

        __builtin_amdgcn_s_setprio(1);
        #pragma unroll
        for (int ks = 0; ks < 2; ++ks)
            #pragma unroll
            for (int m = 0; m < 4; ++m)
                #pragma unroll
                for (int n = 0; n < 2; ++n)
                    acc[m][n] = __builtin_amdgcn_mfma_f32_16x16x32_bf16(
                        bfr[t & 1][n][ks], af[m][ks], acc[m][n], 0, 0, 0);
        __builtin_amdgcn_s_setprio(0);
        __builtin_amdgcn_sched_barrier(0);

        if (t < NT - 2)       asm volatile("s_waitcnt vmcnt(2)" ::: "memory");
        else if (t == NT - 2) asm volatile("s_waitcnt vmcnt(0)" ::: "memory");
        if (t < NT - 1) __builtin_amdgcn_s_barrier();
    }

    // ---- epilogue through LDS: two 64-row passes, full-line nt stores ----
    #pragma unroll
    for (int h = 0; h < 2; ++h) {
        __syncthreads();
        if (wr == h) {
            #pragma unroll
            for (int m = 0; m < 4; ++m) {
                const int row_l = m * 16 + rl;             // 0..63
                #pragma unroll
                for (int n = 0; n < 2; ++n) {
                    const int col = wc * 32 + n * 16 + koct * 4;   // 0..124
                    *(f32x4*)&s_c[row_l * 132 + col] = acc[m][n];
                }
            }
        }
        __syncthreads();
        #pragma unroll
        for (int rr = 0; rr < 4; ++rr) {
            const int idx  = rr * 512 + tid;
            const int row  = idx >> 5;
            const int g4   = (idx & 31) * 4;
            if ((int)brow0 + g4 < OCOLS) {
                const f32x4 v = *(const f32x4*)&s_c[row * 132 + g4];
                __builtin_nontemporal_store(v,
                    (f32x4*)(C + (size_t)(arow0 + h * 64 + row) * OCOLS + brow0 + g4));
            }
        }
    }
}

// ---------------------------------------------------------------------------
extern "C" void kernel_launch(void* const* d_in, const int* in_sizes, int n_in,
                              void* d_out, int out_size, void* d_ws, size_t ws_size,
                              hipStream_t stream)
{
    const float* sk  = (const float*)d_in[0];   // (16,16,125,12)
    const float* ang = (const float*)d_in[1];   // (32000,25)
    const float* W   = (const float*)d_in[2];   // (12,720)
    const float* TP  = (const float*)d_in[3];   // (2704,2704)
    float* out = (float*)d_out;                 // (32000,2704)

    __hip_bfloat16* X  = (__hip_bfloat16*)d_ws;             // N_ROWS*KST bf16 (20.5 MB)
    __hip_bfloat16* Vb = X + (size_t)N_ROWS * KST;          // OPAD*KST bf16 (1.8 MB)

    prep<<<OPAD + 4000, 320, 0, stream>>>(TP, W, sk, ang, Vb, X);

    dim3 grid(OPAD / 128, N_ROWS / 128);   // (22, 250)
    gemm_bt<<<grid, 512, 0, stream>>>(X, Vb, out);
}

// Round 12
// 174.571 us; speedup vs baseline: 1.1849x; 1.1849x over previous
//
#include <hip/hip_runtime.h>
#include <hip/hip_bf16.h>

// Problem geometry
#define N_ROWS 32000   // Q_OUT*Q_IN*NUM_P
#define SB     12      // SCALAR_BASIS
#define FC     720     // FILTER_C
#define FD     2704    // FILTER_DIM
#define OCOLS  2704    // DIM_OUT*DIM_IN
#define OPAD   2816    // OCOLS padded (44*64)
#define ANGD   25
#define PDIM   300     // SB * ANGD
#define KST    320     // PDIM padded to 10*32
#define NT     10      // K tiles of 32

typedef __attribute__((ext_vector_type(8))) short bf16x8;
typedef __attribute__((ext_vector_type(4))) float f32x4;

__device__ __forceinline__ void gload16(const void* g, void* l) {
    __builtin_amdgcn_global_load_lds(
        (const __attribute__((address_space(1))) void*)g,
        (__attribute__((address_space(3))) void*)l, 16, 0, 0);
}

// ---------------------------------------------------------------------------
// Kernel A (round-9 proven): V[o, s*25+a] = sum_c TP[o,...]*(W[s,...]/sqrt12)
// ---------------------------------------------------------------------------
__global__ __launch_bounds__(320) void build_V(
    const float* __restrict__ TP,
    const float* __restrict__ W,
    __hip_bfloat16* __restrict__ V)
{
    const int o   = blockIdx.x;   // 0..OPAD-1
    const int tid = threadIdx.x;  // 0..319
    __shared__ float s_tp[FD];        // 10816 B
    __shared__ float s_w[SB * FC];    // 34560 B

    const float inv = 0.28867513459481288f; // 1/sqrt(12)
    for (int i = tid; i < SB * FC; i += 320) s_w[i] = W[i] * inv;
    if (o < OCOLS) {
        for (int i = tid; i < FD; i += 320) s_tp[i] = TP[(size_t)o * FD + i];
    } else {
        for (int i = tid; i < FD; i += 320) s_tp[i] = 0.f;
    }
    __syncthreads();

    const int p = tid;   // one p per thread
    float acc = 0.f;
    if (p < PDIM) {
        const int s     = p / ANGD;
        const int alpha = p - s * ANGD;
        int m, off, sco, al, Cl;
        if (alpha < 1)       { m = 1; off = 0;    sco = 0;   al = 0;  Cl = 144; }
        else if (alpha < 4)  { m = 3; off = 144;  sco = 144; al = 1;  Cl = 272; }
        else if (alpha < 9)  { m = 5; off = 960;  sco = 416; al = 4;  Cl = 208; }
        else if (alpha < 16) { m = 7; off = 2000; sco = 624; al = 9;  Cl = 80;  }
        else                 { m = 9; off = 2560; sco = 704; al = 16; Cl = 16;  }
        const int j = alpha - al;
        const float* tp = s_tp + off + j;
        const float* ww = s_w + s * FC + sco;
        float a0 = 0.f, a1 = 0.f, a2 = 0.f, a3 = 0.f;
        for (int c = 0; c < Cl; c += 4) {
            a0 += tp[(c + 0) * m] * ww[c + 0];
            a1 += tp[(c + 1) * m] * ww[c + 1];
            a2 += tp[(c + 2) * m] * ww[c + 2];
            a3 += tp[(c + 3) * m] * ww[c + 3];
        }
        acc = (a0 + a1) + (a2 + a3);
    }
    if (p < KST) V[(size_t)o * KST + p] = __float2bfloat16(acc);
}

// ---------------------------------------------------------------------------
// Kernel B (round-9 proven): X[n, s*25+a] = sk[n,s] * ang[n,a], bf16.
// ---------------------------------------------------------------------------
__global__ void build_X(const float* __restrict__ sk,
                        const float* __restrict__ ang,
                        __hip_bfloat16* __restrict__ X)
{
    const int idx = blockIdx.x * 256 + threadIdx.x;
    if (idx >= N_ROWS * (KST / 8)) return;
    const int n  = idx / (KST / 8);
    const int p0 = (idx - n * (KST / 8)) * 8;
    const float* skn  = sk  + (size_t)n * SB;
    const float* angn = ang + (size_t)n * ANGD;
    alignas(16) __hip_bfloat16 tmp[8];
    #pragma unroll
    for (int u = 0; u < 8; ++u) {
        const int p = p0 + u;
        float v = 0.f;
        if (p < PDIM) {
            const int s = p / ANGD;
            const int a = p - s * ANGD;
            v = skn[s] * angn[a];
        }
        tmp[u] = __float2bfloat16(v);
    }
    *(bf16x8*)(X + (size_t)n * KST + p0) = *(const bf16x8*)tmp;
}

// ---------------------------------------------------------------------------
// Kernel C: OCCUPANCY-TUNED GEMM. Tile 128x64, 256 threads (4 waves, 2Mx2N,
// per-wave 64x32), BK=32, LDS 24 KiB (A 2x8K + B 2x4K; epilogue alias 17K)
// -> ~5 blocks/CU, 20 waves/CU (was 2 blocks/16 waves). Same verified
// skeleton: swizzled gload_lds staging, swizzled ds_read_b128, swapped
// MFMA -> D^T frags, LDS-routed full-line nt epilogue.
// BK=32 swizzle: read slot = koct ^ (rl&3) ^ ((rl>>2)&3)  (2-way = free);
// stage source slot = (lane&3) ^ ((lane>>2)&3) ^ ((lane>>4)&3), linear dest.
// vmcnt ledger (per thread, 3 loads per STAGE): prologue 6 -> vmcnt(3);
// iter t: +3 (t+2) after barrier; end-of-iter vmcnt(3) leaves t+2 only
// (t=NT-2: vmcnt(0)).
// ---------------------------------------------------------------------------
__global__ __launch_bounds__(256, 4) void gemm_bt(
    const __hip_bfloat16* __restrict__ A,   // X: (N_ROWS, KST)
    const __hip_bfloat16* __restrict__ B,   // V: (OPAD, KST)
    float* __restrict__ C)
{
    __shared__ __align__(1024) char lds[24576];
    char* const bufA = lds;            // 2 x 8192 B
    char* const bufB = lds + 16384;    // 2 x 4096 B
    float* const s_c = (float*)lds;    // epilogue alias: [64][68] f32 (17408 B)

    const int tid  = threadIdx.x;
    const int wave = tid >> 6;         // 0..3
    const int lane = tid & 63;

    const int bn = blockIdx.x;         // 44 col tiles (64 cols each)
    const int bm = blockIdx.y;         // 250 row tiles (128 rows each)
    const size_t arow0 = (size_t)bm * 128;
    const size_t brow0 = (size_t)bn * 64;

    const int wr = wave >> 1;   // 0..1 (M half: 64 rows)
    const int wc = wave & 1;    // 0..1 (N half: 32 cols)

    // staging: lane -> row lrow2 = lane>>2 within 16-row group, slot lane&3.
    const int lrow2 = lane >> 2;
    const int sslot = (((lane & 3) ^ (lrow2 & 3) ^ ((lane >> 4) & 3))) << 4;

    auto STAGE = [&](int t, int half) {
        char* const la = bufA + half * 8192;
        char* const lb = bufB + half * 4096;
        // A tile [128][32]: wave covers rows wave*16.. and +64
        const char* ga = (const char*)A
            + (arow0 + (size_t)(wave * 16 + lrow2)) * (KST * 2)
            + (size_t)t * 64 + sslot;
        gload16(ga,                          la + wave * 1024);
        gload16(ga + (size_t)64 * (KST * 2), la + 4096 + wave * 1024);
        // B tile [64][32]: wave covers rows wave*16..
        const char* gb = (const char*)B
            + (brow0 + (size_t)(wave * 16 + lrow2)) * (KST * 2)
            + (size_t)t * 64 + sslot;
        gload16(gb, lb + wave * 1024);
    };

    // reader constants
    const int rl   = lane & 15;
    const int koct = lane >> 4;
    const int rslot = ((koct ^ (rl & 3) ^ ((rl >> 2) & 3))) << 4;

    // prologue: stage t0 -> half0, t1 -> half1
    STAGE(0, 0);
    STAGE(1, 1);
    asm volatile("s_waitcnt vmcnt(3)" ::: "memory");
    __builtin_amdgcn_s_barrier();

    f32x4 acc[4][2] = {};   // [m][n]; D^T frags: row=o, col=M

    for (int t = 0; t < NT; ++t) {
        char* const aC = bufA + (t & 1) * 8192;
        char* const bC = bufB + (t & 1) * 4096;

        bf16x8 af[4], bfr[2];
        #pragma unroll
        for (int m = 0; m < 4; ++m) {
            const int r = wr * 64 + m * 16 + rl;
            af[m] = *(const bf16x8*)(aC + r * 64 + rslot);
        }
        #pragma unroll
        for (int n = 0; n < 2; ++n) {
            const int r = wc * 32 + n * 16 + rl;
            bfr[n] = *(const bf16x8*)(bC + r * 64 + rslot);
        }
        asm volatile("s_waitcnt lgkmcnt(0)" ::: "memory");
        __builtin_amdgcn_sched_barrier(0);
        __builtin_amdgcn_s_barrier();   // all waves done reading this half

        if (t + 2 < NT) STAGE(t + 2, t & 1);   // refill the half just read

        __builtin_amdgcn_s_setprio(1);
        #pragma unroll
        for (int m = 0; m < 4; ++m)
            #pragma unroll
            for (int n = 0; n < 2; ++n)
                acc[m][n] = __builtin_amdgcn_mfma_f32_16x16x32_bf16(
                    bfr[n], af[m], acc[m][n], 0, 0, 0);
        __builtin_amdgcn_s_setprio(0);
        __builtin_amdgcn_sched_barrier(0);

        if (t < NT - 2)       asm volatile("s_waitcnt vmcnt(3)" ::: "memory");
        else if (t == NT - 2) asm volatile("s_waitcnt vmcnt(0)" ::: "memory");
        if (t < NT - 1) __builtin_amdgcn_s_barrier();
    }

    // ---- epilogue through LDS: two 64-row passes, full-line nt stores ----
    // acc[m][n]: M = arow0 + wr*64 + m*16 + rl; o = brow0 + wc*32 + n*16 + koct*4
    #pragma unroll
    for (int h = 0; h < 2; ++h) {
        __syncthreads();
        if (wr == h) {
            #pragma unroll
            for (int m = 0; m < 4; ++m) {
                const int row_l = m * 16 + rl;                    // 0..63
                #pragma unroll
                for (int n = 0; n < 2; ++n) {
                    const int col = wc * 32 + n * 16 + koct * 4;  // 0..60
                    *(f32x4*)&s_c[row_l * 68 + col] = acc[m][n];
                }
            }
        }
        __syncthreads();
        // read back linearly: 64 rows x 16 f32x4-groups = 1024 groups
        #pragma unroll
        for (int rr = 0; rr < 4; ++rr) {
            const int idx = rr * 256 + tid;
            const int row = idx >> 4;
            const int g4  = (idx & 15) * 4;
            if ((int)brow0 + g4 < OCOLS) {
                const f32x4 v = *(const f32x4*)&s_c[row * 68 + g4];
                __builtin_nontemporal_store(v,
                    (f32x4*)(C + (size_t)(arow0 + h * 64 + row) * OCOLS + brow0 + g4));
            }
        }
    }
}

// ---------------------------------------------------------------------------
extern "C" void kernel_launch(void* const* d_in, const int* in_sizes, int n_in,
                              void* d_out, int out_size, void* d_ws, size_t ws_size,
                              hipStream_t stream)
{
    const float* sk  = (const float*)d_in[0];   // (16,16,125,12)
    const float* ang = (const float*)d_in[1];   // (32000,25)
    const float* W   = (const float*)d_in[2];   // (12,720)
    const float* TP  = (const float*)d_in[3];   // (2704,2704)
    float* out = (float*)d_out;                 // (32000,2704)

    __hip_bfloat16* X  = (__hip_bfloat16*)d_ws;             // N_ROWS*KST bf16 (20.5 MB)
    __hip_bfloat16* Vb = X + (size_t)N_ROWS * KST;          // OPAD*KST bf16 (1.8 MB)

    build_V<<<OPAD, 320, 0, stream>>>(TP, W, Vb);
    build_X<<<(N_ROWS * (KST / 8) + 255) / 256, 256, 0, stream>>>(sk, ang, X);

    dim3 grid(OPAD / 64, N_ROWS / 128);   // (44, 250)
    gemm_bt<<<grid, 256, 0, stream>>>(X, Vb, out);
}